// Round 5
// baseline (1150.831 us; speedup 1.0000x reference)
//
#include <hip/hip_runtime.h>
#include <math.h>

// NSVQ: N=262144 rows, D=64, K=1024 codebooks.
// d_out (fp32): [N*D] quantized | [1] perplexity | [K] counts_new.
//
// v6: arithmetic-intensity fix. Evidence v1-v5: barriers (neutral), wave
// count (worse), no-LDS/global-B (worse) -- the knob never varied was
// rows/wave. At 32 rows/wave, per chunk a wave's 16 ds_read_b128 feed only
// 48 MFMAs with ~190 dependent argmin VALU ops: MFMA/VALU/LDS pipes all
// within 2x -> dependency stalls hit every pipe (the 28/33% signature).
// Now 64 rows/wave (4 rowsets): same 16 LDS reads feed 96 MFMAs (16
// independent 6-chains of ILP); MFMA dominates ~4x. Same verified f16
// hi/lo 6-MFMA arithmetic (absmax 2.0). Finalize merged into fused via
// last-block ticket (saves one graph node of launch overhead).

#define NROWS 262144
#define DIM 64
#define KCODES 1024
#define ND ((size_t)NROWS * DIM)

typedef __attribute__((ext_vector_type(8))) _Float16 f16x8;  // 4 VGPRs
typedef __attribute__((ext_vector_type(4))) float f32x4;

typedef const __attribute__((address_space(1))) void* as1p;
typedef __attribute__((address_space(3))) void* as3p;
__device__ inline void gl_lds16(const void* g, void* l) {
    __builtin_amdgcn_global_load_lds((as1p)g, (as3p)l, 16, 0, 0);
}

// --- prep: swizzled f16 hi/lo of -2c + fp32 norms + zero counts/ticket --
// cbs layout (halfs): 64-code chunk c0=k>>6 (8192 halfs = 16 KB each):
//   hi unit (u=j>>3, c=k&63) at c0*8192 + u*512 + c*8 ; lo at +4096
__global__ __launch_bounds__(256) void nsvq_prep(
    const float* __restrict__ cb, _Float16* __restrict__ cbs,
    float* __restrict__ cnorm, unsigned int* __restrict__ counts,
    unsigned int* __restrict__ ticket)
{
    const int tid = blockIdx.x * 256 + threadIdx.x;   // 8192 total
    if (tid < KCODES) counts[tid] = 0u;               // replaces memset node
    if (tid == 0) *ticket = 0u;
    const int k = tid >> 3;
    const int u = tid & 7;
    const float* p = cb + (size_t)k * DIM + u * 8;
    float4 f0 = *(const float4*)p;
    float4 f1 = *(const float4*)(p + 4);
    float fv[8] = {f0.x, f0.y, f0.z, f0.w, f1.x, f1.y, f1.z, f1.w};

    float s = 0.f;
    f16x8 hv, lv;
#pragma unroll
    for (int j = 0; j < 8; ++j) {
        s = fmaf(fv[j], fv[j], s);
        float m2 = -2.0f * fv[j];
        _Float16 h = (_Float16)m2;
        hv[j] = h;
        lv[j] = (_Float16)(m2 - (float)h);
    }
#pragma unroll
    for (int o = 1; o < 8; o <<= 1) s += __shfl_xor(s, o, 64);

    const size_t base = (size_t)(k >> 6) * 8192 + (size_t)u * 512 + (size_t)(k & 63) * 8;
    *(f16x8*)(cbs + base) = hv;
    *(f16x8*)(cbs + base + 4096) = lv;
    if (u == 0) cnorm[k] = s;
}

// --- fused main ---------------------------------------------------------
// block = 4 waves = 256 rows; wave = 64 rows (4 rowsets of 16).
// lane = (q = dim-octet 0..3, n = row/code-col 0..15).
// LDS = 2 x 16 KB chunk buffers; 16 chunks of 64 codes.
__global__ __launch_bounds__(256, 2) void nsvq_fused(
    const float* __restrict__ x, const float* __restrict__ rv,
    const _Float16* __restrict__ cbs, const float* __restrict__ cnorm,
    const int* __restrict__ used, float* __restrict__ out,
    unsigned int* __restrict__ counts, unsigned int* __restrict__ ticket)
{
    __shared__ _Float16 lds[16384];   // 32 KB

    const int tid  = threadIdx.x;
    const int lane = tid & 63;
    const int wave = tid >> 6;        // 0..3
    const int q    = lane >> 4;
    const int n    = lane & 15;
    const int wBase = blockIdx.x * 256 + wave * 64;

    // ---- stage chunk 0 (issue first so it overlaps the x-frag build) ----
#pragma unroll
    for (int r = 0; r < 4; ++r) {
        const int off = (r * 256 + tid) * 8;     // halfs, lane-contiguous 16 B
        gl_lds16(cbs + off, lds + off);
    }

    // ---- A: x rows -> f16 hi/lo frags + ||x||^2 (fp32 exact) ----
    f16x8 ah[4][2], al[4][2];
    float xx[4];
#pragma unroll
    for (int s = 0; s < 4; ++s) {
        const int row = wBase + s * 16 + n;
        const float* px = x + (size_t)row * DIM + q * 8;
        float acc = 0.f;
#pragma unroll
        for (int c2 = 0; c2 < 2; ++c2) {
            float4 g0 = *(const float4*)(px + c2 * 32);
            float4 g1 = *(const float4*)(px + c2 * 32 + 4);
            float fv[8] = {g0.x, g0.y, g0.z, g0.w, g1.x, g1.y, g1.z, g1.w};
#pragma unroll
            for (int j = 0; j < 8; ++j) {
                float f = fv[j];
                acc = fmaf(f, f, acc);
                _Float16 h = (_Float16)f;
                ah[s][c2][j] = h;
                al[s][c2][j] = (_Float16)(f - (float)h);
            }
        }
        acc += __shfl_xor(acc, 16, 64);
        acc += __shfl_xor(acc, 32, 64);
        xx[s] = acc;
    }

    float cn_cur[4], cn_nxt[4];
#pragma unroll
    for (int t = 0; t < 4; ++t) cn_cur[t] = cnorm[t * 16 + n];

    float best[4][4];
    int   bidx[4][4];
#pragma unroll
    for (int s = 0; s < 4; ++s)
#pragma unroll
        for (int r = 0; r < 4; ++r) { best[s][r] = 3.4e38f; bidx[s][r] = 0; }

    __syncthreads();   // chunk 0 staged (compiler drains vmcnt here)

    auto compute_chunk = [&](int b, int cbase) {
        const _Float16* buf = lds + b * 8192;
#pragma unroll
        for (int t = 0; t < 4; ++t) {
            const int ci = (t * 16 + n) * 8;
            f16x8 bh0 = *(const f16x8*)(buf + q * 512 + ci);
            f16x8 bh1 = *(const f16x8*)(buf + (q + 4) * 512 + ci);
            f16x8 bl0 = *(const f16x8*)(buf + 4096 + q * 512 + ci);
            f16x8 bl1 = *(const f16x8*)(buf + 4096 + (q + 4) * 512 + ci);
            const int code = cbase + t * 16 + n;
#pragma unroll
            for (int s = 0; s < 4; ++s) {
                f32x4 a = {cn_cur[t], cn_cur[t], cn_cur[t], cn_cur[t]};  // ||c||^2
                a = __builtin_amdgcn_mfma_f32_16x16x32_f16(ah[s][0], bh0, a, 0, 0, 0);
                a = __builtin_amdgcn_mfma_f32_16x16x32_f16(ah[s][1], bh1, a, 0, 0, 0);
                a = __builtin_amdgcn_mfma_f32_16x16x32_f16(al[s][0], bh0, a, 0, 0, 0);
                a = __builtin_amdgcn_mfma_f32_16x16x32_f16(al[s][1], bh1, a, 0, 0, 0);
                a = __builtin_amdgcn_mfma_f32_16x16x32_f16(ah[s][0], bl0, a, 0, 0, 0);
                a = __builtin_amdgcn_mfma_f32_16x16x32_f16(ah[s][1], bl1, a, 0, 0, 0);
#pragma unroll
                for (int r = 0; r < 4; ++r) {
                    if (a[r] < best[s][r]) { best[s][r] = a[r]; bidx[s][r] = code; }
                }
            }
        }
    };

#pragma unroll 2
    for (int c = 0; c < 15; ++c) {
        const int b = c & 1;
        // issue next-chunk stage + cnorm prefetch BEFORE computing current
        {
            const _Float16* src = cbs + (size_t)(c + 1) * 8192;
            _Float16* dst = lds + (b ^ 1) * 8192;
#pragma unroll
            for (int r = 0; r < 4; ++r) {
                const int off = (r * 256 + tid) * 8;
                gl_lds16(src + off, dst + off);
            }
#pragma unroll
            for (int t = 0; t < 4; ++t) cn_nxt[t] = cnorm[(c + 1) * 64 + t * 16 + n];
        }
        compute_chunk(b, c * 64);
        __syncthreads();   // drains the prefetch; everyone done reading buf b
#pragma unroll
        for (int t = 0; t < 4; ++t) cn_cur[t] = cn_nxt[t];
    }
    compute_chunk(1, 15 * 64);   // last chunk, no prefetch, no barrier needed

    // ---- cross-lane argmin over the 16 code-lanes ----
#pragma unroll
    for (int o = 1; o < 16; o <<= 1) {
#pragma unroll
        for (int s = 0; s < 4; ++s)
#pragma unroll
            for (int r = 0; r < 4; ++r) {
                float od = __shfl_xor(best[s][r], o, 64);
                int   ok = __shfl_xor(bidx[s][r], o, 64);
                if (od < best[s][r] || (od == best[s][r] && ok < bidx[s][r])) {
                    best[s][r] = od; bidx[s][r] = ok;
                }
            }
    }
    // lane (q,*) now holds winners for rows s*16 + q*4 + r.
    if (n == 0) {
#pragma unroll
        for (int s = 0; s < 4; ++s)
#pragma unroll
            for (int r = 0; r < 4; ++r) atomicAdd(&counts[bidx[s][r]], 1u);
    }

    // ---- route winner dist to row lanes via shuffle ----
    const int src = ((n >> 2) << 4) | n;
#pragma unroll
    for (int s = 0; s < 4; ++s) {
        float w0 = __shfl(best[s][0], src, 64);
        float w1 = __shfl(best[s][1], src, 64);
        float w2 = __shfl(best[s][2], src, 64);
        float w3 = __shfl(best[s][3], src, 64);
        float wa = (n & 1) ? w1 : w0;
        float wb = (n & 1) ? w3 : w2;
        float dmin = (n & 2) ? wb : wa;

        float res2 = xx[s] + dmin;
        if (res2 < 0.f) res2 = 0.f;
        const float resn = sqrtf(res2);

        const int row = wBase + s * 16 + n;
        const float* pr = rv + (size_t)row * DIM + q * 8;
        float rvf[16];
        float rr = 0.f;
#pragma unroll
        for (int c2 = 0; c2 < 2; ++c2) {
            float4 g0 = *(const float4*)(pr + c2 * 32);
            float4 g1 = *(const float4*)(pr + c2 * 32 + 4);
            rvf[c2 * 8 + 0] = g0.x; rvf[c2 * 8 + 1] = g0.y;
            rvf[c2 * 8 + 2] = g0.z; rvf[c2 * 8 + 3] = g0.w;
            rvf[c2 * 8 + 4] = g1.x; rvf[c2 * 8 + 5] = g1.y;
            rvf[c2 * 8 + 6] = g1.z; rvf[c2 * 8 + 7] = g1.w;
#pragma unroll
            for (int j = 0; j < 8; ++j) rr = fmaf(rvf[c2 * 8 + j], rvf[c2 * 8 + j], rr);
        }
        rr += __shfl_xor(rr, 16, 64);
        rr += __shfl_xor(rr, 32, 64);
        const float scale = resn / (sqrtf(rr) + 1e-12f);

        // x reconstructed from f16 hi+lo (error ~|x|*2^-23)
        float* po = out + (size_t)row * DIM + q * 8;
#pragma unroll
        for (int c2 = 0; c2 < 2; ++c2) {
            float4 o0, o1;
            o0.x = fmaf(scale, rvf[c2 * 8 + 0], (float)ah[s][c2][0] + (float)al[s][c2][0]);
            o0.y = fmaf(scale, rvf[c2 * 8 + 1], (float)ah[s][c2][1] + (float)al[s][c2][1]);
            o0.z = fmaf(scale, rvf[c2 * 8 + 2], (float)ah[s][c2][2] + (float)al[s][c2][2]);
            o0.w = fmaf(scale, rvf[c2 * 8 + 3], (float)ah[s][c2][3] + (float)al[s][c2][3]);
            o1.x = fmaf(scale, rvf[c2 * 8 + 4], (float)ah[s][c2][4] + (float)al[s][c2][4]);
            o1.y = fmaf(scale, rvf[c2 * 8 + 5], (float)ah[s][c2][5] + (float)al[s][c2][5]);
            o1.z = fmaf(scale, rvf[c2 * 8 + 6], (float)ah[s][c2][6] + (float)al[s][c2][6]);
            o1.w = fmaf(scale, rvf[c2 * 8 + 7], (float)ah[s][c2][7] + (float)al[s][c2][7]);
            *(float4*)(po + c2 * 32) = o0;
            *(float4*)(po + c2 * 32 + 4) = o1;
        }
    }

    // ---- last-block finalize (replaces separate kernel) ----
    __shared__ unsigned lastflag;
    if (tid == 0) {
        __threadfence();   // release: counts atomics visible before ticket
        lastflag = (atomicAdd(ticket, 1u) == (unsigned)(gridDim.x - 1)) ? 1u : 0u;
    }
    __syncthreads();
    if (lastflag) {
        __threadfence();   // acquire
        float term = 0.f;
#pragma unroll
        for (int kk = 0; kk < 4; ++kk) {
            const int k = kk * 256 + tid;
            const unsigned c = atomicAdd(&counts[k], 0u);   // coherent read
            out[ND + 1 + k] = (float)(c + (unsigned)used[k]);
            const float avg = (float)c * (1.0f / (float)NROWS);
            term += (c > 0) ? (-avg * logf(avg + 1e-12f)) : 0.0f;
        }
#pragma unroll
        for (int o = 32; o > 0; o >>= 1) term += __shfl_down(term, o, 64);
        float* part = (float*)lds;
        if ((tid & 63) == 0) part[tid >> 6] = term;
        __syncthreads();
        if (tid == 0) out[ND] = expf(part[0] + part[1] + part[2] + part[3]);
    }
}

extern "C" void kernel_launch(void* const* d_in, const int* in_sizes, int n_in,
                              void* d_out, int out_size, void* d_ws, size_t ws_size,
                              hipStream_t stream) {
    const float* x    = (const float*)d_in[0];
    const float* rv   = (const float*)d_in[1];
    const float* cb   = (const float*)d_in[2];
    const int*   used = (const int*)d_in[3];
    float* out = (float*)d_out;

    char* ws = (char*)d_ws;
    unsigned int* counts = (unsigned int*)ws;                 // 4 KB
    float*        cnorm  = (float*)(ws + 4096);               // 4 KB
    _Float16*     cbs    = (_Float16*)(ws + 8192);            // 256 KB f16 hi/lo -2c
    unsigned int* ticket = (unsigned int*)(ws + 8192 + 262144);

    nsvq_prep<<<KCODES * 8 / 256, 256, 0, stream>>>(cb, cbs, cnorm, counts, ticket);
    nsvq_fused<<<NROWS / 256, 256, 0, stream>>>(x, rv, cbs, cnorm, used, out, counts, ticket);
}

// Round 7
// 448.404 us; speedup vs baseline: 2.5665x; 2.5665x over previous
//
#include <hip/hip_runtime.h>
#include <math.h>

// NSVQ: N=262144 rows, D=64, K=1024 codebooks.
// d_out (fp32): [N*D] quantized | [1] perplexity | [K] counts_new.
//
// v7b: resubmit of v7 (R6 bench died to container-infra failure, no
// signal). B-resident GEMM structure. v1-v6 evidence: barrier tuning
// neutral, occupancy hurts, global-B streaming hurts, bigger row tiles
// spill. Root flaw everywhere: codebook restaged into LDS 8-16x per block
// and every B-frag re-read from LDS per chunk. Correct orientation for
// M=262k/N=1024/K=64: codebook strips RESIDENT IN REGISTERS (64 codes
// f16 hi/lo = 64 VGPR per wave; 8 waves x 64 = 512 codes per half, 2
// halves swapped per round from L2), x rows streamed through LDS as f16
// hi/lo (staged once ever, XOR-swizzled -> bank-balanced ds_read_b128
// frag loads, zero inner-loop cvt). Per wave per round: 384 MFMAs between
// barriers (v3: 48). Partial argmin per 64-code strip -> LDS [128][8]
// min-merge -> per-round in-block reduce + epilogue. launch_bounds(512,2)
// caps VGPR at 256: spill impossible (v6 lesson). Same verified f16 hi/lo
// 6-MFMA distance arithmetic (absmax 2.0).

#define NROWS 262144
#define DIM 64
#define KCODES 1024
#define ND ((size_t)NROWS * DIM)
#define RPB 512        // rows per block
#define RND 128        // rows per round

typedef __attribute__((ext_vector_type(8))) _Float16 f16x8;  // 4 VGPRs
typedef __attribute__((ext_vector_type(4))) float f32x4;

// --- prep: swizzled f16 hi/lo of -2c + fp32 norms + zero counts ---------
// cbs layout (halfs): 64-code chunk c0=k>>6 (8192 halfs = 16 KB each):
//   hi unit (u=j>>3, c=k&63) at c0*8192 + u*512 + c*8 ; lo at +4096
// chunk c0 == (half*8 + wave): exactly one wave's resident strip.
__global__ __launch_bounds__(256) void nsvq_prep(
    const float* __restrict__ cb, _Float16* __restrict__ cbs,
    float* __restrict__ cnorm, unsigned int* __restrict__ counts)
{
    const int tid = blockIdx.x * 256 + threadIdx.x;   // 8192 total
    if (tid < KCODES) counts[tid] = 0u;               // replaces memset node
    const int k = tid >> 3;
    const int u = tid & 7;
    const float* p = cb + (size_t)k * DIM + u * 8;
    float4 f0 = *(const float4*)p;
    float4 f1 = *(const float4*)(p + 4);
    float fv[8] = {f0.x, f0.y, f0.z, f0.w, f1.x, f1.y, f1.z, f1.w};

    float s = 0.f;
    f16x8 hv, lv;
#pragma unroll
    for (int j = 0; j < 8; ++j) {
        s = fmaf(fv[j], fv[j], s);
        float m2 = -2.0f * fv[j];
        _Float16 h = (_Float16)m2;
        hv[j] = h;
        lv[j] = (_Float16)(m2 - (float)h);
    }
#pragma unroll
    for (int o = 1; o < 8; o <<= 1) s += __shfl_xor(s, o, 64);

    const size_t base = (size_t)(k >> 6) * 8192 + (size_t)u * 512 + (size_t)(k & 63) * 8;
    *(f16x8*)(cbs + base) = hv;
    *(f16x8*)(cbs + base + 4096) = lv;
    if (u == 0) cnorm[k] = s;
}

// --- fused main ---------------------------------------------------------
// 512 threads = 8 waves. Wave w holds codes {h*512 + w*64 ..+63} (h=0,1
// swapped per round). Rounds of 128 rows staged in LDS as f16 hi/lo.
// lane = (q = k-octet 0..3, n = row/code-col 0..15).
__global__ __launch_bounds__(512, 2) void nsvq_fused(
    const float* __restrict__ x, const float* __restrict__ rv,
    const _Float16* __restrict__ cbs, const float* __restrict__ cnorm,
    float* __restrict__ out, unsigned int* __restrict__ counts)
{
    __shared__ _Float16 xhi[2][RND * DIM];   // 16 KB each buf
    __shared__ _Float16 xlo[2][RND * DIM];
    __shared__ float pdist[RND][8];          // per-wave partials
    __shared__ int   pidx[RND][8];

    const int tid  = threadIdx.x;
    const int lane = tid & 63;
    const int wave = tid >> 6;        // 0..7
    const int q    = lane >> 4;
    const int n    = lane & 15;
    const size_t rowBase = (size_t)blockIdx.x * RPB;

    // per-wave code norms, both halves, loaded once
    float cn[2][4];
#pragma unroll
    for (int h = 0; h < 2; ++h)
#pragma unroll
        for (int t = 0; t < 4; ++t)
            cn[h][t] = cnorm[h * 512 + wave * 64 + t * 16 + n];

    f16x8 bh[4][2], bl[4][2];   // resident strip: [codetile][k-half]

    // staging map: thread -> row tid>>2, dims (tid&3)*16..+15
    const int srow = tid >> 2;

    auto stage_write = [&](int bufTo, const float4* sx) {
#pragma unroll
        for (int g = 0; g < 2; ++g) {
            float fv[8] = {sx[2*g].x, sx[2*g].y, sx[2*g].z, sx[2*g].w,
                           sx[2*g+1].x, sx[2*g+1].y, sx[2*g+1].z, sx[2*g+1].w};
            f16x8 hv, lv;
#pragma unroll
            for (int j = 0; j < 8; ++j) {
                _Float16 hh = (_Float16)fv[j];
                hv[j] = hh;
                lv[j] = (_Float16)(fv[j] - (float)hh);
            }
            const int phys = ((tid & 3) * 2 + g) ^ (srow & 7);   // slot swizzle
            *(f16x8*)&xhi[bufTo][srow * DIM + phys * 8] = hv;
            *(f16x8*)&xlo[bufTo][srow * DIM + phys * 8] = lv;
        }
    };

    auto loadB = [&](int half) {
        const _Float16* cp = cbs + (size_t)(half * 8 + wave) * 8192;
#pragma unroll
        for (int ct = 0; ct < 4; ++ct) {
            const int ci = (ct * 16 + n) * 8;
            bh[ct][0] = *(const f16x8*)(cp + q * 512 + ci);
            bh[ct][1] = *(const f16x8*)(cp + (q + 4) * 512 + ci);
            bl[ct][0] = *(const f16x8*)(cp + 4096 + q * 512 + ci);
            bl[ct][1] = *(const f16x8*)(cp + 4096 + (q + 4) * 512 + ci);
        }
    };

    auto compute_half = [&](int b, int h) {
#pragma unroll 2
        for (int rt = 0; rt < 8; ++rt) {
            const int arow = rt * 16 + n;
            const int rbase = arow * DIM;
            const int sw = n & 7;                      // arow & 7 == n & 7
            f16x8 ah0 = *(const f16x8*)&xhi[b][rbase + ((q ^ sw) * 8)];
            f16x8 ah1 = *(const f16x8*)&xhi[b][rbase + (((4 + q) ^ sw) * 8)];
            f16x8 al0 = *(const f16x8*)&xlo[b][rbase + ((q ^ sw) * 8)];
            f16x8 al1 = *(const f16x8*)&xlo[b][rbase + (((4 + q) ^ sw) * 8)];

            f32x4 acc[4];
#pragma unroll
            for (int ct = 0; ct < 4; ++ct)
                acc[ct] = (f32x4){cn[h][ct], cn[h][ct], cn[h][ct], cn[h][ct]};
#pragma unroll
            for (int ct = 0; ct < 4; ++ct) {   // 4 independent 6-chains (ILP)
                acc[ct] = __builtin_amdgcn_mfma_f32_16x16x32_f16(ah0, bh[ct][0], acc[ct], 0, 0, 0);
                acc[ct] = __builtin_amdgcn_mfma_f32_16x16x32_f16(ah1, bh[ct][1], acc[ct], 0, 0, 0);
                acc[ct] = __builtin_amdgcn_mfma_f32_16x16x32_f16(al0, bh[ct][0], acc[ct], 0, 0, 0);
                acc[ct] = __builtin_amdgcn_mfma_f32_16x16x32_f16(al1, bh[ct][1], acc[ct], 0, 0, 0);
                acc[ct] = __builtin_amdgcn_mfma_f32_16x16x32_f16(ah0, bl[ct][0], acc[ct], 0, 0, 0);
                acc[ct] = __builtin_amdgcn_mfma_f32_16x16x32_f16(ah1, bl[ct][1], acc[ct], 0, 0, 0);
            }

            // per-lane best over the 4 codetiles (full tie-break)
            float best[4]; int bidx[4];
            const int cb0 = h * 512 + wave * 64 + n;
#pragma unroll
            for (int r = 0; r < 4; ++r) { best[r] = acc[0][r]; bidx[r] = cb0; }
#pragma unroll
            for (int ct = 1; ct < 4; ++ct) {
                const int code = cb0 + ct * 16;
#pragma unroll
                for (int r = 0; r < 4; ++r) {
                    const float d = acc[ct][r];
                    if (d < best[r] || (d == best[r] && code < bidx[r])) {
                        best[r] = d; bidx[r] = code;
                    }
                }
            }
            // reduce across the 16 code-lanes
#pragma unroll
            for (int o = 1; o < 16; o <<= 1) {
#pragma unroll
                for (int r = 0; r < 4; ++r) {
                    const float od = __shfl_xor(best[r], o, 64);
                    const int   ok = __shfl_xor(bidx[r], o, 64);
                    if (od < best[r] || (od == best[r] && ok < bidx[r])) {
                        best[r] = od; bidx[r] = ok;
                    }
                }
            }
            if (n == 0) {   // lane (q,0) owns rows rt*16 + q*4 + r
#pragma unroll
                for (int r = 0; r < 4; ++r) {
                    const int prow = rt * 16 + q * 4 + r;
                    if (h == 0) {
                        pdist[prow][wave] = best[r];
                        pidx[prow][wave]  = bidx[r];
                    } else {
                        const float pd = pdist[prow][wave];
                        const int   pi = pidx[prow][wave];
                        if (best[r] < pd || (best[r] == pd && bidx[r] < pi)) {
                            pdist[prow][wave] = best[r];
                            pidx[prow][wave]  = bidx[r];
                        }
                    }
                }
            }
        }
    };

    auto epilogue = [&](int rr2, int b) {
        const int prow = wave * 16 + (lane >> 2);     // wave's 16 rows
        const size_t rowG = rowBase + (size_t)rr2 * RND + prow;
        // final argmin over the 8 wave-columns (scalar reads, ordered)
        float bd = pdist[prow][0]; int bi = pidx[prow][0];
#pragma unroll
        for (int w2 = 1; w2 < 8; ++w2) {
            const float d = pdist[prow][w2]; const int i = pidx[prow][w2];
            if (d < bd || (d == bd && i < bi)) { bd = d; bi = i; }
        }
        if ((lane & 3) == 0) atomicAdd(&counts[bi], 1u);

        // x reconstruct (f16 hi+lo, ~2^-23 rel err) + ||x||^2
        const int ed0 = (lane & 3) * 16;
        const int esw = prow & 7;
        float xr[16];
        float xx = 0.f;
#pragma unroll
        for (int g = 0; g < 2; ++g) {
            const int phys = ((lane & 3) * 2 + g) ^ esw;
            f16x8 hh = *(const f16x8*)&xhi[b][prow * DIM + phys * 8];
            f16x8 ll = *(const f16x8*)&xlo[b][prow * DIM + phys * 8];
#pragma unroll
            for (int j = 0; j < 8; ++j) {
                const float f = (float)hh[j] + (float)ll[j];
                xr[g * 8 + j] = f;
                xx = fmaf(f, f, xx);
            }
        }
        xx += __shfl_xor(xx, 1, 64);
        xx += __shfl_xor(xx, 2, 64);

        float res2 = xx + bd;
        if (res2 < 0.f) res2 = 0.f;
        const float resn = sqrtf(res2);

        const float* pr = rv + rowG * DIM + ed0;
        float4 g0 = ((const float4*)pr)[0];
        float4 g1 = ((const float4*)pr)[1];
        float4 g2 = ((const float4*)pr)[2];
        float4 g3 = ((const float4*)pr)[3];
        float rvf[16] = {g0.x, g0.y, g0.z, g0.w, g1.x, g1.y, g1.z, g1.w,
                         g2.x, g2.y, g2.z, g2.w, g3.x, g3.y, g3.z, g3.w};
        float rr_ = 0.f;
#pragma unroll
        for (int j = 0; j < 16; ++j) rr_ = fmaf(rvf[j], rvf[j], rr_);
        rr_ += __shfl_xor(rr_, 1, 64);
        rr_ += __shfl_xor(rr_, 2, 64);
        const float scale = resn / (sqrtf(rr_) + 1e-12f);

        float* po = out + rowG * DIM + ed0;
#pragma unroll
        for (int g = 0; g < 4; ++g) {
            float4 o4;
            o4.x = fmaf(scale, rvf[g * 4 + 0], xr[g * 4 + 0]);
            o4.y = fmaf(scale, rvf[g * 4 + 1], xr[g * 4 + 1]);
            o4.z = fmaf(scale, rvf[g * 4 + 2], xr[g * 4 + 2]);
            o4.w = fmaf(scale, rvf[g * 4 + 3], xr[g * 4 + 3]);
            ((float4*)po)[g] = o4;
        }
    };

    // ---- prologue: stage round 0 ----
    {
        const float* p = x + (rowBase + srow) * DIM + (tid & 3) * 16;
        float4 sx[4] = {((const float4*)p)[0], ((const float4*)p)[1],
                        ((const float4*)p)[2], ((const float4*)p)[3]};
        stage_write(0, sx);
    }
    __syncthreads();

#pragma unroll 1
    for (int rr2 = 0; rr2 < 4; ++rr2) {
        const int b = rr2 & 1;
        float4 sx[4];
        if (rr2 < 3) {   // T14: issue next-round loads before compute
            const float* p = x + (rowBase + (size_t)(rr2 + 1) * RND + srow) * DIM + (tid & 3) * 16;
            sx[0] = ((const float4*)p)[0]; sx[1] = ((const float4*)p)[1];
            sx[2] = ((const float4*)p)[2]; sx[3] = ((const float4*)p)[3];
        }
        loadB(0);
        compute_half(b, 0);
        if (rr2 < 3) stage_write(b ^ 1, sx);   // HBM latency hidden under half 0
        loadB(1);
        compute_half(b, 1);
        __syncthreads();        // partials complete
        epilogue(rr2, b);
        __syncthreads();        // partial + x buffers free for next round
    }
}

// --- finalize: perplexity + counts output -------------------------------
__global__ void nsvq_finalize(const unsigned int* __restrict__ counts,
                              const int* __restrict__ used,
                              float* __restrict__ out)
{
    const int k = threadIdx.x;  // 1024 threads
    const unsigned c = counts[k];
    float avg = (float)c * (1.0f / (float)NROWS);
    float term = (c > 0) ? (-avg * logf(avg + 1e-12f)) : 0.0f;

    float v = term;
#pragma unroll
    for (int o = 32; o > 0; o >>= 1) v += __shfl_down(v, o, 64);

    __shared__ float partial[16];
    if ((threadIdx.x & 63) == 0) partial[threadIdx.x >> 6] = v;
    __syncthreads();

    if (threadIdx.x < 64) {
        float s = (threadIdx.x < 16) ? partial[threadIdx.x] : 0.0f;
#pragma unroll
        for (int o = 32; o > 0; o >>= 1) s += __shfl_down(s, o, 64);
        if (threadIdx.x == 0) out[ND] = expf(s);
    }
    out[ND + 1 + k] = (float)(c + (unsigned)used[k]);
}

extern "C" void kernel_launch(void* const* d_in, const int* in_sizes, int n_in,
                              void* d_out, int out_size, void* d_ws, size_t ws_size,
                              hipStream_t stream) {
    const float* x    = (const float*)d_in[0];
    const float* rv   = (const float*)d_in[1];
    const float* cb   = (const float*)d_in[2];
    const int*   used = (const int*)d_in[3];
    float* out = (float*)d_out;

    char* ws = (char*)d_ws;
    unsigned int* counts = (unsigned int*)ws;                 // 4 KB
    float*        cnorm  = (float*)(ws + 4096);               // 4 KB
    _Float16*     cbs    = (_Float16*)(ws + 8192);            // 256 KB f16 hi/lo -2c

    nsvq_prep<<<KCODES * 8 / 256, 256, 0, stream>>>(cb, cbs, cnorm, counts);
    nsvq_fused<<<NROWS / RPB, 512, 0, stream>>>(x, rv, cbs, cnorm, out, counts);
    nsvq_finalize<<<1, KCODES, 0, stream>>>(counts, used, out);
}

// Round 8
// 425.896 us; speedup vs baseline: 2.7021x; 1.0528x over previous
//
#include <hip/hip_runtime.h>
#include <math.h>

// NSVQ: N=262144 rows, D=64, K=1024 codebooks.
// d_out (fp32): [N*D] quantized | [1] perplexity | [K] counts_new.
//
// v8: v3 (151us verified, absmax 2.0, 0 bank conflicts) + T3/T4 counted-
// vmcnt pipeline. v3's profile (Mfma 28 / VALU 33 / both idle ~70%) is the
// m233 2-phase signature: the critical path is the full vmcnt(0) drain at
// every barrier. Fix per the proven recipe (m218: +38-73%): 3 LDS chunk
// buffers, prefetch depth 2, per-phase {issue stage(c+2); compute c;
// s_waitcnt vmcnt(4) -- c+1 landed, c+2 STILL IN FLIGHT; raw s_barrier;
// sched_barrier(0)}. vmcnt hits 0 only at phase 14. cnorm staged to LDS
// once so the loop has no other VMEM ops (hand counts stay exact).
// setprio(1) around MFMA cluster (T5 -- phase-split now exists).
// Argmin in registers until one final reduce (v7's in-loop reduction +
// 4.6M bank conflicts reverted). Arithmetic identical to v3.

#define NROWS 262144
#define DIM 64
#define KCODES 1024
#define ND ((size_t)NROWS * DIM)

typedef __attribute__((ext_vector_type(8))) _Float16 f16x8;  // 4 VGPRs
typedef __attribute__((ext_vector_type(4))) float f32x4;

typedef const __attribute__((address_space(1))) void* as1p;
typedef __attribute__((address_space(3))) void* as3p;
__device__ inline void gl_lds16(const void* g, void* l) {
    __builtin_amdgcn_global_load_lds((as1p)g, (as3p)l, 16, 0, 0);
}

// --- prep: swizzled f16 hi/lo of -2c + fp32 norms + zero counts ---------
// cbs layout (halfs): 64-code chunk c0=k>>6 (8192 halfs = 16 KB each):
//   hi unit (u=j>>3, c=k&63) at c0*8192 + u*512 + c*8 ; lo at +4096
__global__ __launch_bounds__(256) void nsvq_prep(
    const float* __restrict__ cb, _Float16* __restrict__ cbs,
    float* __restrict__ cnorm, unsigned int* __restrict__ counts)
{
    const int tid = blockIdx.x * 256 + threadIdx.x;   // 8192 total
    if (tid < KCODES) counts[tid] = 0u;               // replaces memset node
    const int k = tid >> 3;
    const int u = tid & 7;
    const float* p = cb + (size_t)k * DIM + u * 8;
    float4 f0 = *(const float4*)p;
    float4 f1 = *(const float4*)(p + 4);
    float fv[8] = {f0.x, f0.y, f0.z, f0.w, f1.x, f1.y, f1.z, f1.w};

    float s = 0.f;
    f16x8 hv, lv;
#pragma unroll
    for (int j = 0; j < 8; ++j) {
        s = fmaf(fv[j], fv[j], s);
        float m2 = -2.0f * fv[j];
        _Float16 h = (_Float16)m2;
        hv[j] = h;
        lv[j] = (_Float16)(m2 - (float)h);
    }
#pragma unroll
    for (int o = 1; o < 8; o <<= 1) s += __shfl_xor(s, o, 64);

    const size_t base = (size_t)(k >> 6) * 8192 + (size_t)u * 512 + (size_t)(k & 63) * 8;
    *(f16x8*)(cbs + base) = hv;
    *(f16x8*)(cbs + base + 4096) = lv;
    if (u == 0) cnorm[k] = s;
}

// --- fused main ---------------------------------------------------------
// block = 4 waves = 128 rows; wave = 32 rows (2 rowsets of 16).
// lane = (q = dim-octet 0..3, n = row/code-col 0..15).
// LDS = 3 x 16 KB chunk buffers + 4 KB cnorm; 16 chunks of 64 codes.
__global__ __launch_bounds__(256, 4) void nsvq_fused(
    const float* __restrict__ x, const float* __restrict__ rv,
    const _Float16* __restrict__ cbs, const float* __restrict__ cnorm,
    float* __restrict__ out, unsigned int* __restrict__ counts)
{
    __shared__ _Float16 lds[3 * 8192 + 2048];   // 48 KB bufs + 4 KB cnorm
    float* cnf = (float*)(lds + 3 * 8192);

    const int tid  = threadIdx.x;
    const int lane = tid & 63;
    const int wave = tid >> 6;
    const int q    = lane >> 4;
    const int n    = lane & 15;
    const int wBase = blockIdx.x * 128 + wave * 32;

    // ---- A: x rows -> f16 hi/lo frags + ||x||^2 FIRST (its loads retire
    // before the hand-counted pipeline begins) ----
    f16x8 ah[2][2], al[2][2];
    float xx[2];
#pragma unroll
    for (int s = 0; s < 2; ++s) {
        const int row = wBase + s * 16 + n;
        const float* px = x + (size_t)row * DIM + q * 8;
        float acc = 0.f;
#pragma unroll
        for (int c2 = 0; c2 < 2; ++c2) {
            float4 g0 = *(const float4*)(px + c2 * 32);
            float4 g1 = *(const float4*)(px + c2 * 32 + 4);
            float fv[8] = {g0.x, g0.y, g0.z, g0.w, g1.x, g1.y, g1.z, g1.w};
#pragma unroll
            for (int j = 0; j < 8; ++j) {
                float f = fv[j];
                acc = fmaf(f, f, acc);
                _Float16 h = (_Float16)f;
                ah[s][c2][j] = h;
                al[s][c2][j] = (_Float16)(f - (float)h);
            }
        }
        acc += __shfl_xor(acc, 16, 64);
        acc += __shfl_xor(acc, 32, 64);
        xx[s] = acc;
    }

    // ---- issue: cnorm->LDS (1 load), stage(0) (4), stage(1) (4) ----
    gl_lds16(cnorm + tid * 4, cnf + tid * 4);
#pragma unroll
    for (int r = 0; r < 4; ++r) {
        const int off = (r * 256 + tid) * 8;
        gl_lds16(cbs + off, lds + off);
    }
#pragma unroll
    for (int r = 0; r < 4; ++r) {
        const int off = (r * 256 + tid) * 8;
        gl_lds16(cbs + 8192 + off, lds + 8192 + off);
    }

    float best[2][4];
    int   bidx[2][4];
#pragma unroll
    for (int s = 0; s < 2; ++s)
#pragma unroll
        for (int r = 0; r < 4; ++r) { best[s][r] = 3.4e38f; bidx[s][r] = 0; }

    // cnorm + stage(0) done (5 oldest); stage(1)'s 4 stay in flight
    asm volatile("s_waitcnt vmcnt(4)" ::: "memory");
    __builtin_amdgcn_s_barrier();
    __builtin_amdgcn_sched_barrier(0);

#pragma unroll
    for (int c = 0; c < 16; ++c) {
        const _Float16* buf = lds + (c % 3) * 8192;

        if (c < 14) {   // prefetch chunk c+2 into the buffer freed by phase c-1
            const _Float16* src = cbs + (size_t)(c + 2) * 8192;
            _Float16* dst = lds + ((c + 2) % 3) * 8192;
#pragma unroll
            for (int r = 0; r < 4; ++r) {
                const int off = (r * 256 + tid) * 8;
                gl_lds16(src + off, dst + off);
            }
        }

        float cn[4];
#pragma unroll
        for (int t = 0; t < 4; ++t) cn[t] = cnf[c * 64 + t * 16 + n];

        __builtin_amdgcn_s_setprio(1);
#pragma unroll
        for (int t = 0; t < 4; ++t) {
            const int ci = (t * 16 + n) * 8;
            f16x8 bh0 = *(const f16x8*)(buf + q * 512 + ci);
            f16x8 bh1 = *(const f16x8*)(buf + (q + 4) * 512 + ci);
            f16x8 bl0 = *(const f16x8*)(buf + 4096 + q * 512 + ci);
            f16x8 bl1 = *(const f16x8*)(buf + 4096 + (q + 4) * 512 + ci);
            const int code = c * 64 + t * 16 + n;
#pragma unroll
            for (int s = 0; s < 2; ++s) {
                f32x4 a = {cn[t], cn[t], cn[t], cn[t]};  // C-init = ||c||^2
                a = __builtin_amdgcn_mfma_f32_16x16x32_f16(ah[s][0], bh0, a, 0, 0, 0);
                a = __builtin_amdgcn_mfma_f32_16x16x32_f16(ah[s][1], bh1, a, 0, 0, 0);
                a = __builtin_amdgcn_mfma_f32_16x16x32_f16(al[s][0], bh0, a, 0, 0, 0);
                a = __builtin_amdgcn_mfma_f32_16x16x32_f16(al[s][1], bh1, a, 0, 0, 0);
                a = __builtin_amdgcn_mfma_f32_16x16x32_f16(ah[s][0], bl0, a, 0, 0, 0);
                a = __builtin_amdgcn_mfma_f32_16x16x32_f16(ah[s][1], bl1, a, 0, 0, 0);
#pragma unroll
                for (int r = 0; r < 4; ++r) {
                    if (a[r] < best[s][r]) { best[s][r] = a[r]; bidx[s][r] = code; }
                }
            }
        }
        __builtin_amdgcn_s_setprio(0);

        if (c < 15) {
            // counted wait: c+1's 4 loads retired; c+2's (if any) in flight
            if (c < 14) asm volatile("s_waitcnt vmcnt(4)" ::: "memory");
            else        asm volatile("s_waitcnt vmcnt(0)" ::: "memory");
            __builtin_amdgcn_s_barrier();
            __builtin_amdgcn_sched_barrier(0);
        }
    }

    // ---- cross-lane argmin over the 16 code-lanes (ONCE) ----
#pragma unroll
    for (int o = 1; o < 16; o <<= 1) {
#pragma unroll
        for (int s = 0; s < 2; ++s)
#pragma unroll
            for (int r = 0; r < 4; ++r) {
                float od = __shfl_xor(best[s][r], o, 64);
                int   ok = __shfl_xor(bidx[s][r], o, 64);
                if (od < best[s][r] || (od == best[s][r] && ok < bidx[s][r])) {
                    best[s][r] = od; bidx[s][r] = ok;
                }
            }
    }
    // lane (q,*) now holds winners for rows s*16 + q*4 + r.
    if (n == 0) {
#pragma unroll
        for (int s = 0; s < 2; ++s)
#pragma unroll
            for (int r = 0; r < 4; ++r) atomicAdd(&counts[bidx[s][r]], 1u);
    }

    // ---- route winner dist to row lanes via shuffle ----
    const int src = ((n >> 2) << 4) | n;
#pragma unroll
    for (int s = 0; s < 2; ++s) {
        float w0 = __shfl(best[s][0], src, 64);
        float w1 = __shfl(best[s][1], src, 64);
        float w2 = __shfl(best[s][2], src, 64);
        float w3 = __shfl(best[s][3], src, 64);
        float wa = (n & 1) ? w1 : w0;
        float wb = (n & 1) ? w3 : w2;
        float dmin = (n & 2) ? wb : wa;

        float res2 = xx[s] + dmin;
        if (res2 < 0.f) res2 = 0.f;
        const float resn = sqrtf(res2);

        const int row = wBase + s * 16 + n;
        const float* pr = rv + (size_t)row * DIM + q * 8;
        float rvf[16];
        float rr = 0.f;
#pragma unroll
        for (int c2 = 0; c2 < 2; ++c2) {
            float4 g0 = *(const float4*)(pr + c2 * 32);
            float4 g1 = *(const float4*)(pr + c2 * 32 + 4);
            rvf[c2 * 8 + 0] = g0.x; rvf[c2 * 8 + 1] = g0.y;
            rvf[c2 * 8 + 2] = g0.z; rvf[c2 * 8 + 3] = g0.w;
            rvf[c2 * 8 + 4] = g1.x; rvf[c2 * 8 + 5] = g1.y;
            rvf[c2 * 8 + 6] = g1.z; rvf[c2 * 8 + 7] = g1.w;
#pragma unroll
            for (int j = 0; j < 8; ++j) rr = fmaf(rvf[c2 * 8 + j], rvf[c2 * 8 + j], rr);
        }
        rr += __shfl_xor(rr, 16, 64);
        rr += __shfl_xor(rr, 32, 64);
        const float scale = resn / (sqrtf(rr) + 1e-12f);

        // x reconstructed from f16 hi+lo (error ~|x|*2^-23)
        float* po = out + (size_t)row * DIM + q * 8;
#pragma unroll
        for (int c2 = 0; c2 < 2; ++c2) {
            float4 o0, o1;
            o0.x = fmaf(scale, rvf[c2 * 8 + 0], (float)ah[s][c2][0] + (float)al[s][c2][0]);
            o0.y = fmaf(scale, rvf[c2 * 8 + 1], (float)ah[s][c2][1] + (float)al[s][c2][1]);
            o0.z = fmaf(scale, rvf[c2 * 8 + 2], (float)ah[s][c2][2] + (float)al[s][c2][2]);
            o0.w = fmaf(scale, rvf[c2 * 8 + 3], (float)ah[s][c2][3] + (float)al[s][c2][3]);
            o1.x = fmaf(scale, rvf[c2 * 8 + 4], (float)ah[s][c2][4] + (float)al[s][c2][4]);
            o1.y = fmaf(scale, rvf[c2 * 8 + 5], (float)ah[s][c2][5] + (float)al[s][c2][5]);
            o1.z = fmaf(scale, rvf[c2 * 8 + 6], (float)ah[s][c2][6] + (float)al[s][c2][6]);
            o1.w = fmaf(scale, rvf[c2 * 8 + 7], (float)ah[s][c2][7] + (float)al[s][c2][7]);
            *(float4*)(po + c2 * 32) = o0;
            *(float4*)(po + c2 * 32 + 4) = o1;
        }
    }
}

// --- finalize: perplexity + counts output -------------------------------
__global__ void nsvq_finalize(const unsigned int* __restrict__ counts,
                              const int* __restrict__ used,
                              float* __restrict__ out)
{
    const int k = threadIdx.x;  // 1024 threads
    const unsigned c = counts[k];
    float avg = (float)c * (1.0f / (float)NROWS);
    float term = (c > 0) ? (-avg * logf(avg + 1e-12f)) : 0.0f;

    float v = term;
#pragma unroll
    for (int o = 32; o > 0; o >>= 1) v += __shfl_down(v, o, 64);

    __shared__ float partial[16];
    if ((threadIdx.x & 63) == 0) partial[threadIdx.x >> 6] = v;
    __syncthreads();

    if (threadIdx.x < 64) {
        float s = (threadIdx.x < 16) ? partial[threadIdx.x] : 0.0f;
#pragma unroll
        for (int o = 32; o > 0; o >>= 1) s += __shfl_down(s, o, 64);
        if (threadIdx.x == 0) out[ND] = expf(s);
    }
    out[ND + 1 + k] = (float)(c + (unsigned)used[k]);
}

extern "C" void kernel_launch(void* const* d_in, const int* in_sizes, int n_in,
                              void* d_out, int out_size, void* d_ws, size_t ws_size,
                              hipStream_t stream) {
    const float* x    = (const float*)d_in[0];
    const float* rv   = (const float*)d_in[1];
    const float* cb   = (const float*)d_in[2];
    const int*   used = (const int*)d_in[3];
    float* out = (float*)d_out;

    char* ws = (char*)d_ws;
    unsigned int* counts = (unsigned int*)ws;                 // 4 KB
    float*        cnorm  = (float*)(ws + 4096);               // 4 KB
    _Float16*     cbs    = (_Float16*)(ws + 8192);            // 256 KB f16 hi/lo -2c

    nsvq_prep<<<KCODES * 8 / 256, 256, 0, stream>>>(cb, cbs, cnorm, counts);
    nsvq_fused<<<NROWS / 128, 256, 0, stream>>>(x, rv, cbs, cnorm, out, counts);
    nsvq_finalize<<<1, KCODES, 0, stream>>>(counts, used, out);
}

// Round 9
// 276.030 us; speedup vs baseline: 4.1692x; 1.5429x over previous
//
#include <hip/hip_runtime.h>
#include <math.h>

// NSVQ: N=262144 rows, D=64, K=1024 codebooks.
// d_out (fp32): [N*D] quantized | [1] perplexity | [K] counts_new.
//
// v9: counted-vmcnt pipeline, MINIMAL port onto the verified v3 skeleton.
// v8 failed by implementation (VGPR 256 + 440 MB scratch: full unroll +
// sched_barrier(0) pinning blew regalloc), not by idea. v9 keeps v3's
// code body byte-for-byte and changes ONLY the sync structure:
//   - 3 LDS chunk buffers (depth-2 prefetch), ROLLED loop (#pragma unroll 1)
//   - per phase: issue stage(c+2); compute c; s_waitcnt vmcnt(4) (c+1
//     retired, c+2 STILL IN FLIGHT); raw s_barrier. vmcnt->0 only at c=14.
//   - cnorm staged to LDS once (loop has no other VMEM -> counts exact)
//   - setprio(1) around MFMA cluster (register-neutral)
// Safety gates: no sched_barrier(0), no full unroll, VGPR must stay <=128.

#define NROWS 262144
#define DIM 64
#define KCODES 1024
#define ND ((size_t)NROWS * DIM)

typedef __attribute__((ext_vector_type(8))) _Float16 f16x8;  // 4 VGPRs
typedef __attribute__((ext_vector_type(4))) float f32x4;

typedef const __attribute__((address_space(1))) void* as1p;
typedef __attribute__((address_space(3))) void* as3p;
__device__ inline void gl_lds16(const void* g, void* l) {
    __builtin_amdgcn_global_load_lds((as1p)g, (as3p)l, 16, 0, 0);
}

// --- prep: swizzled f16 hi/lo of -2c + fp32 norms + zero counts ---------
// cbs layout (halfs): 64-code chunk c0=k>>6 (8192 halfs = 16 KB each):
//   hi unit (u=j>>3, c=k&63) at c0*8192 + u*512 + c*8 ; lo at +4096
__global__ __launch_bounds__(256) void nsvq_prep(
    const float* __restrict__ cb, _Float16* __restrict__ cbs,
    float* __restrict__ cnorm, unsigned int* __restrict__ counts)
{
    const int tid = blockIdx.x * 256 + threadIdx.x;   // 8192 total
    if (tid < KCODES) counts[tid] = 0u;               // replaces memset node
    const int k = tid >> 3;
    const int u = tid & 7;
    const float* p = cb + (size_t)k * DIM + u * 8;
    float4 f0 = *(const float4*)p;
    float4 f1 = *(const float4*)(p + 4);
    float fv[8] = {f0.x, f0.y, f0.z, f0.w, f1.x, f1.y, f1.z, f1.w};

    float s = 0.f;
    f16x8 hv, lv;
#pragma unroll
    for (int j = 0; j < 8; ++j) {
        s = fmaf(fv[j], fv[j], s);
        float m2 = -2.0f * fv[j];
        _Float16 h = (_Float16)m2;
        hv[j] = h;
        lv[j] = (_Float16)(m2 - (float)h);
    }
#pragma unroll
    for (int o = 1; o < 8; o <<= 1) s += __shfl_xor(s, o, 64);

    const size_t base = (size_t)(k >> 6) * 8192 + (size_t)u * 512 + (size_t)(k & 63) * 8;
    *(f16x8*)(cbs + base) = hv;
    *(f16x8*)(cbs + base + 4096) = lv;
    if (u == 0) cnorm[k] = s;
}

// --- fused main ---------------------------------------------------------
// block = 4 waves = 128 rows; wave = 32 rows (2 rowsets of 16).
// lane = (q = dim-octet 0..3, n = row/code-col 0..15).
// LDS = 3 x 16 KB chunk buffers + 4 KB cnorm; 16 chunks of 64 codes.
__global__ __launch_bounds__(256, 4) void nsvq_fused(
    const float* __restrict__ x, const float* __restrict__ rv,
    const _Float16* __restrict__ cbs, const float* __restrict__ cnorm,
    float* __restrict__ out, unsigned int* __restrict__ counts)
{
    __shared__ _Float16 lds[3 * 8192 + 2048];   // 48 KB bufs + 4 KB cnorm
    float* cnf = (float*)(lds + 3 * 8192);

    const int tid  = threadIdx.x;
    const int lane = tid & 63;
    const int wave = tid >> 6;
    const int q    = lane >> 4;
    const int n    = lane & 15;
    const int wBase = blockIdx.x * 128 + wave * 32;

    // ---- issue: cnorm->LDS (1 load), stage chunk0 (4), chunk1 (4) ----
    gl_lds16(cnorm + tid * 4, cnf + tid * 4);
#pragma unroll
    for (int r = 0; r < 4; ++r) {
        const int off = (r * 256 + tid) * 8;
        gl_lds16(cbs + off, lds + off);
    }
#pragma unroll
    for (int r = 0; r < 4; ++r) {
        const int off = (r * 256 + tid) * 8;
        gl_lds16(cbs + 8192 + off, lds + 8192 + off);
    }

    // ---- A: x rows -> f16 hi/lo frags + ||x||^2 (fp32 exact) ----
    f16x8 ah[2][2], al[2][2];
    float xx[2];
#pragma unroll
    for (int s = 0; s < 2; ++s) {
        const int row = wBase + s * 16 + n;
        const float* px = x + (size_t)row * DIM + q * 8;
        float acc = 0.f;
#pragma unroll
        for (int c2 = 0; c2 < 2; ++c2) {
            float4 g0 = *(const float4*)(px + c2 * 32);
            float4 g1 = *(const float4*)(px + c2 * 32 + 4);
            float fv[8] = {g0.x, g0.y, g0.z, g0.w, g1.x, g1.y, g1.z, g1.w};
#pragma unroll
            for (int j = 0; j < 8; ++j) {
                float f = fv[j];
                acc = fmaf(f, f, acc);
                _Float16 h = (_Float16)f;
                ah[s][c2][j] = h;
                al[s][c2][j] = (_Float16)(f - (float)h);
            }
        }
        acc += __shfl_xor(acc, 16, 64);
        acc += __shfl_xor(acc, 32, 64);
        xx[s] = acc;
    }

    float best[2][4];
    int   bidx[2][4];
#pragma unroll
    for (int s = 0; s < 2; ++s)
#pragma unroll
        for (int r = 0; r < 4; ++r) { best[s][r] = 3.4e38f; bidx[s][r] = 0; }

    // cnorm + chunk0 retired (5 oldest); chunk1's 4 may stay in flight
    asm volatile("s_waitcnt vmcnt(4)" ::: "memory");
    __builtin_amdgcn_s_barrier();

#pragma unroll 1
    for (int c = 0; c < 16; ++c) {
        const _Float16* buf = lds + (c % 3) * 8192;

        if (c < 14) {   // prefetch chunk c+2 into the buffer freed at phase c-1
            const _Float16* src = cbs + (size_t)(c + 2) * 8192;
            _Float16* dst = lds + ((c + 2) % 3) * 8192;
#pragma unroll
            for (int r = 0; r < 4; ++r) {
                const int off = (r * 256 + tid) * 8;
                gl_lds16(src + off, dst + off);
            }
        }

        float cn[4];
#pragma unroll
        for (int t = 0; t < 4; ++t) cn[t] = cnf[c * 64 + t * 16 + n];

        __builtin_amdgcn_s_setprio(1);
#pragma unroll
        for (int t = 0; t < 4; ++t) {
            const int ci = (t * 16 + n) * 8;
            f16x8 bh0 = *(const f16x8*)(buf + q * 512 + ci);
            f16x8 bh1 = *(const f16x8*)(buf + (q + 4) * 512 + ci);
            f16x8 bl0 = *(const f16x8*)(buf + 4096 + q * 512 + ci);
            f16x8 bl1 = *(const f16x8*)(buf + 4096 + (q + 4) * 512 + ci);
            const int code = c * 64 + t * 16 + n;
#pragma unroll
            for (int s = 0; s < 2; ++s) {
                f32x4 a = {cn[t], cn[t], cn[t], cn[t]};  // C-init = ||c||^2
                a = __builtin_amdgcn_mfma_f32_16x16x32_f16(ah[s][0], bh0, a, 0, 0, 0);
                a = __builtin_amdgcn_mfma_f32_16x16x32_f16(ah[s][1], bh1, a, 0, 0, 0);
                a = __builtin_amdgcn_mfma_f32_16x16x32_f16(al[s][0], bh0, a, 0, 0, 0);
                a = __builtin_amdgcn_mfma_f32_16x16x32_f16(al[s][1], bh1, a, 0, 0, 0);
                a = __builtin_amdgcn_mfma_f32_16x16x32_f16(ah[s][0], bl0, a, 0, 0, 0);
                a = __builtin_amdgcn_mfma_f32_16x16x32_f16(ah[s][1], bl1, a, 0, 0, 0);
#pragma unroll
                for (int r = 0; r < 4; ++r) {
                    if (a[r] < best[s][r]) { best[s][r] = a[r]; bidx[s][r] = code; }
                }
            }
        }
        __builtin_amdgcn_s_setprio(0);

        if (c < 14) {
            asm volatile("s_waitcnt vmcnt(4)" ::: "memory");  // c+1 retired, c+2 in flight
            __builtin_amdgcn_s_barrier();
        } else if (c == 14) {
            asm volatile("s_waitcnt vmcnt(0)" ::: "memory");  // chunk 15 retired
            __builtin_amdgcn_s_barrier();
        }
    }

    // ---- cross-lane argmin over the 16 code-lanes (ONCE) ----
#pragma unroll
    for (int o = 1; o < 16; o <<= 1) {
#pragma unroll
        for (int s = 0; s < 2; ++s)
#pragma unroll
            for (int r = 0; r < 4; ++r) {
                float od = __shfl_xor(best[s][r], o, 64);
                int   ok = __shfl_xor(bidx[s][r], o, 64);
                if (od < best[s][r] || (od == best[s][r] && ok < bidx[s][r])) {
                    best[s][r] = od; bidx[s][r] = ok;
                }
            }
    }
    // lane (q,*) now holds winners for rows s*16 + q*4 + r.
    if (n == 0) {
#pragma unroll
        for (int s = 0; s < 2; ++s)
#pragma unroll
            for (int r = 0; r < 4; ++r) atomicAdd(&counts[bidx[s][r]], 1u);
    }

    // ---- route winner dist to row lanes via shuffle ----
    const int src = ((n >> 2) << 4) | n;
#pragma unroll
    for (int s = 0; s < 2; ++s) {
        float w0 = __shfl(best[s][0], src, 64);
        float w1 = __shfl(best[s][1], src, 64);
        float w2 = __shfl(best[s][2], src, 64);
        float w3 = __shfl(best[s][3], src, 64);
        float wa = (n & 1) ? w1 : w0;
        float wb = (n & 1) ? w3 : w2;
        float dmin = (n & 2) ? wb : wa;

        float res2 = xx[s] + dmin;
        if (res2 < 0.f) res2 = 0.f;
        const float resn = sqrtf(res2);

        const int row = wBase + s * 16 + n;
        const float* pr = rv + (size_t)row * DIM + q * 8;
        float rvf[16];
        float rr = 0.f;
#pragma unroll
        for (int c2 = 0; c2 < 2; ++c2) {
            float4 g0 = *(const float4*)(pr + c2 * 32);
            float4 g1 = *(const float4*)(pr + c2 * 32 + 4);
            rvf[c2 * 8 + 0] = g0.x; rvf[c2 * 8 + 1] = g0.y;
            rvf[c2 * 8 + 2] = g0.z; rvf[c2 * 8 + 3] = g0.w;
            rvf[c2 * 8 + 4] = g1.x; rvf[c2 * 8 + 5] = g1.y;
            rvf[c2 * 8 + 6] = g1.z; rvf[c2 * 8 + 7] = g1.w;
#pragma unroll
            for (int j = 0; j < 8; ++j) rr = fmaf(rvf[c2 * 8 + j], rvf[c2 * 8 + j], rr);
        }
        rr += __shfl_xor(rr, 16, 64);
        rr += __shfl_xor(rr, 32, 64);
        const float scale = resn / (sqrtf(rr) + 1e-12f);

        // x reconstructed from f16 hi+lo (error ~|x|*2^-23)
        float* po = out + (size_t)row * DIM + q * 8;
#pragma unroll
        for (int c2 = 0; c2 < 2; ++c2) {
            float4 o0, o1;
            o0.x = fmaf(scale, rvf[c2 * 8 + 0], (float)ah[s][c2][0] + (float)al[s][c2][0]);
            o0.y = fmaf(scale, rvf[c2 * 8 + 1], (float)ah[s][c2][1] + (float)al[s][c2][1]);
            o0.z = fmaf(scale, rvf[c2 * 8 + 2], (float)ah[s][c2][2] + (float)al[s][c2][2]);
            o0.w = fmaf(scale, rvf[c2 * 8 + 3], (float)ah[s][c2][3] + (float)al[s][c2][3]);
            o1.x = fmaf(scale, rvf[c2 * 8 + 4], (float)ah[s][c2][4] + (float)al[s][c2][4]);
            o1.y = fmaf(scale, rvf[c2 * 8 + 5], (float)ah[s][c2][5] + (float)al[s][c2][5]);
            o1.z = fmaf(scale, rvf[c2 * 8 + 6], (float)ah[s][c2][6] + (float)al[s][c2][6]);
            o1.w = fmaf(scale, rvf[c2 * 8 + 7], (float)ah[s][c2][7] + (float)al[s][c2][7]);
            *(float4*)(po + c2 * 32) = o0;
            *(float4*)(po + c2 * 32 + 4) = o1;
        }
    }
}

// --- finalize: perplexity + counts output -------------------------------
__global__ void nsvq_finalize(const unsigned int* __restrict__ counts,
                              const int* __restrict__ used,
                              float* __restrict__ out)
{
    const int k = threadIdx.x;  // 1024 threads
    const unsigned c = counts[k];
    float avg = (float)c * (1.0f / (float)NROWS);
    float term = (c > 0) ? (-avg * logf(avg + 1e-12f)) : 0.0f;

    float v = term;
#pragma unroll
    for (int o = 32; o > 0; o >>= 1) v += __shfl_down(v, o, 64);

    __shared__ float partial[16];
    if ((threadIdx.x & 63) == 0) partial[threadIdx.x >> 6] = v;
    __syncthreads();

    if (threadIdx.x < 64) {
        float s = (threadIdx.x < 16) ? partial[threadIdx.x] : 0.0f;
#pragma unroll
        for (int o = 32; o > 0; o >>= 1) s += __shfl_down(s, o, 64);
        if (threadIdx.x == 0) out[ND] = expf(s);
    }
    out[ND + 1 + k] = (float)(c + (unsigned)used[k]);
}

extern "C" void kernel_launch(void* const* d_in, const int* in_sizes, int n_in,
                              void* d_out, int out_size, void* d_ws, size_t ws_size,
                              hipStream_t stream) {
    const float* x    = (const float*)d_in[0];
    const float* rv   = (const float*)d_in[1];
    const float* cb   = (const float*)d_in[2];
    const int*   used = (const int*)d_in[3];
    float* out = (float*)d_out;

    char* ws = (char*)d_ws;
    unsigned int* counts = (unsigned int*)ws;                 // 4 KB
    float*        cnorm  = (float*)(ws + 4096);               // 4 KB
    _Float16*     cbs    = (_Float16*)(ws + 8192);            // 256 KB f16 hi/lo -2c

    nsvq_prep<<<KCODES * 8 / 256, 256, 0, stream>>>(cb, cbs, cnorm, counts);
    nsvq_fused<<<NROWS / 128, 256, 0, stream>>>(x, rv, cbs, cnorm, out, counts);
    nsvq_finalize<<<1, KCODES, 0, stream>>>(counts, used, out);
}